// Round 4
// baseline (399.467 us; speedup 1.0000x reference)
//
#include <hip/hip_runtime.h>
#include <math.h>

#define HH 6144
#define WW 6144
constexpr int G = 50;
constexpr int NCOPY = 64;
constexpr int NG = NCOPY * G;          // 3200
constexpr int BIG = 0x0FFFFFFF;
constexpr int MINBASE = 4 * NG;        // 12800: min slots (NCOPY uints)
constexpr int CTR = MINBASE + NCOPY;   // 12864: done-counter
constexpr int C0 = CTR + 2;            // 12866 (even -> 8B-aligned doubles)
// const tables (word offsets from C0):
//   dT   [0,100)    tan(th)      f64 x50
//   dRC  [100,200)  rho/cos(th)  f64 x50
//   fva  [200,250)  rho/sin(tv)  f32 x50
//   fvb  [250,300)  cos/sin(tv)  f32 x50
//   dRho [300,400)  rho          f64 x50
//   dSth [400,500)  sin(th)      f64 x50
//   dCth [500,600)  cos(th)      f64 x50
//   dStv [600,700)  sin(tv)      f64 x50
//   dCtv [700,800)  cos(tv)      f64 x50

constexpr int ROWS = 2;
constexpr int TPR  = 256;              // threads per row
constexpr int TPB  = ROWS * TPR;       // 512
constexpr int PXT  = WW / TPR;         // 24 px per thread (<< min boundary spacing)
constexpr int NBLK = HH / ROWS;        // 3072

__device__ inline void ldsAddF(float* p, float v)      { __hip_atomic_fetch_add(p, v, __ATOMIC_RELAXED, __HIP_MEMORY_SCOPE_WORKGROUP); }
__device__ inline void ldsAddU(unsigned* p, unsigned v){ __hip_atomic_fetch_add(p, v, __ATOMIC_RELAXED, __HIP_MEMORY_SCOPE_WORKGROUP); }
__device__ inline void glbAddF(float* p, float v)      { __hip_atomic_fetch_add(p, v, __ATOMIC_RELAXED, __HIP_MEMORY_SCOPE_AGENT); }
__device__ inline void glbAddU(unsigned* p, unsigned v){ __hip_atomic_fetch_add(p, v, __ATOMIC_RELAXED, __HIP_MEMORY_SCOPE_AGENT); }
__device__ inline float atomLoadF(const float* p)      { return __hip_atomic_load(p, __ATOMIC_RELAXED, __HIP_MEMORY_SCOPE_AGENT); }
__device__ inline unsigned atomLoadU(const unsigned* p){ return __hip_atomic_load(p, __ATOMIC_RELAXED, __HIP_MEMORY_SCOPE_AGENT); }

// memset accumulators/min/counter + (block 0, lanes<50) all per-g constants.
__global__ void crop_init(unsigned int* __restrict__ ws,
                          const float* __restrict__ p_rmax,
                          const float* __restrict__ p_rmin,
                          const float* __restrict__ p_thmin,
                          const float* __restrict__ p_thmax,
                          const float* __restrict__ p_tvmin,
                          const float* __restrict__ p_tvmax) {
  int i = blockIdx.x * 256 + threadIdx.x;
  if (i < MINBASE) ws[i] = 0u;
  else if (i < MINBASE + NCOPY) ws[i] = 0x7F800000u;   // +inf bits
  else if (i < C0) ws[i] = 0u;                         // counter + pad

  if (blockIdx.x == 0 && threadIdx.x < G) {
    int t = threadIdx.x;
    double u    = (double)t / (double)(G - 1);
    double rmax = (double)p_rmax[0], rmin = (double)p_rmin[0];
    double rho  = rmax + (rmin - rmax) * u;
    double th   = (double)p_thmin[0] + ((double)p_thmax[0] - (double)p_thmin[0]) * u;
    double tv   = (double)p_tvmin[0] + ((double)p_tvmax[0] - (double)p_tvmin[0]) * u;
    double cth = cos(th), sth = sin(th);
    double ctv = cos(tv), stv = sin(tv);
    double* dT   = (double*)(ws + C0);
    double* dRC  = (double*)(ws + C0 + 100);
    float*  fva  = (float*)(ws + C0 + 200);
    float*  fvb  = (float*)(ws + C0 + 250);
    double* dRho = (double*)(ws + C0 + 300);
    double* dSth = (double*)(ws + C0 + 400);
    double* dCth = (double*)(ws + C0 + 500);
    double* dStv = (double*)(ws + C0 + 600);
    double* dCtv = (double*)(ws + C0 + 700);
    dT[t]  = tan(th);          // same calls as previous passing rounds
    dRC[t] = rho / cth;
    fva[t] = (float)(rho / stv);
    fvb[t] = (float)(ctv / stv);
    dRho[t] = rho; dSth[t] = sth; dCth[t] = cth; dStv[t] = stv; dCtv[t] = ctv;
  }
}

__launch_bounds__(TPB)
__global__ void crop_main(const float* __restrict__ sp,
                          float* __restrict__ wsf,
                          float* __restrict__ out) {
  __shared__ int pxh[ROWS][G], pxv[ROWS][G];   // boundaries, nonincreasing in g
  __shared__ float hsum[G + 1], vsum[G + 1];   // bin G = dropped (segment id 50)
  __shared__ unsigned int hcnt[G + 1], vcnt[G + 1];
  __shared__ float wmin[TPB / 64];
  __shared__ int lastFlag;
  // finalize scratch (only touched by the last block)
  __shared__ double psum[100][4];
  __shared__ unsigned int pcnt[100][4];
  __shared__ double val[100];
  __shared__ float sminv;

  const int t   = threadIdx.x;
  const int bid = blockIdx.x;
  const int r   = t / TPR;
  const int tt  = t - r * TPR;
  const int y   = bid * ROWS + r;
  const int yp  = min(max(y, 1), HH - 2);      // edge-effect fix == clamp of coords
  const int x0  = tt * PXT;

  // issue the pixel loads first (overlap with setup)
  const float4* p4 = (const float4*)(sp + (size_t)y * WW + x0);
  float4 q0 = p4[0], q1 = p4[1], q2 = p4[2], q3 = p4[3], q4 = p4[4], q5 = p4[5];

  for (int i = t; i < G + 1; i += TPB) { hsum[i] = 0.f; vsum[i] = 0.f; hcnt[i] = 0u; vcnt[i] = 0u; }

  const unsigned int* wsu = (const unsigned int*)wsf;
  if (t < 2 * G) {
    const int rr = (t >= G) ? 1 : 0;
    const int g  = t - rr * G;
    const int yq = min(max(bid * ROWS + rr, 1), HH - 2);
    const float fyq = (float)yq;
    const double* dT  = (const double*)(wsu + C0);
    const double* dRC = (const double*)(wsu + C0 + 100);
    const float*  fva = (const float*)(wsu + C0 + 200);
    const float*  fvb = (const float*)(wsu + C0 + 250);

    // horizontal family: f64 fma + half-even rint (same as passing rounds)
    double xg = rint(fma(-(double)yq, dT[g], dRC[g]));
    xg = fmin(fmax(xg, 0.0), (double)(WW - 1));
    int xi = (int)xg;
    pxh[rr][g] = (xi <= 1) ? 0 : (xi >= WW - 1 ? BIG : xi);

    // vertical family: binary-search the EXACT f32 per-pixel condition
    float va = fva[g], vb = fvb[g];
    int lo = 1, hi = WW - 1;
    while (lo < hi) {
      int m = (lo + hi) >> 1;
      float yv = rintf(fmaf(-(float)m, vb, va));
      yv = fminf(fmaxf(yv, 0.f), (float)(HH - 1));
      if (yv <= fyq) hi = m; else lo = m + 1;
    }
    pxv[rr][g] = (lo >= WW - 1) ? BIG : (lo == 1 ? 0 : lo);
  }
  __syncthreads();

  float px[PXT] = { q0.x,q0.y,q0.z,q0.w, q1.x,q1.y,q1.z,q1.w,
                    q2.x,q2.y,q2.z,q2.w, q3.x,q3.y,q3.z,q3.w,
                    q4.x,q4.y,q4.z,q4.w, q5.x,q5.y,q5.z,q5.w };

  // bin at x0: lb = first g with px*[g] <= x0 (arrays nonincreasing in g)
  int lo = 0, hi = G;
  while (lo < hi) { int m = (lo + hi) >> 1; if (pxh[r][m] <= x0) hi = m; else lo = m + 1; }
  const int lbh = lo;
  const int nbh = (lbh > 0) ? pxh[r][lbh - 1] : BIG;
  const int kh  = min(nbh - x0, PXT);          // [1,PXT]; PXT => no crossing in run

  lo = 0; hi = G;
  while (lo < hi) { int m = (lo + hi) >> 1; if (pxv[r][m] <= x0) hi = m; else lo = m + 1; }
  const int lbv = lo;
  const int nbv = (lbv > 0) ? pxv[r][lbv - 1] : BIG;
  const int kv  = min(nbv - x0, PXT);

  const int sh = G - lbh, sv = G - lbv;

  float S = 0.f, Ah = 0.f, Av = 0.f, mn = 3.4e38f;
#pragma unroll
  for (int k = 0; k < PXT; ++k) {
    float v = px[k];
    mn = fminf(mn, v);
    S += v;
    if (k + 1 == kh) Ah = S;
    if (k + 1 == kv) Av = S;
  }

  ldsAddF(&hsum[sh], Ah); ldsAddU(&hcnt[sh], (unsigned)kh);
  if (kh < PXT) { ldsAddF(&hsum[sh + 1], S - Ah); ldsAddU(&hcnt[sh + 1], (unsigned)(PXT - kh)); }
  ldsAddF(&vsum[sv], Av); ldsAddU(&vcnt[sv], (unsigned)kv);
  if (kv < PXT) { ldsAddF(&vsum[sv + 1], S - Av); ldsAddU(&vcnt[sv + 1], (unsigned)(PXT - kv)); }

  // block min reduce (8 waves)
  float m = mn;
  for (int off = 32; off; off >>= 1) m = fminf(m, __shfl_down(m, off));
  if ((t & 63) == 0) wmin[t >> 6] = m;
  __syncthreads();

  const int copy = bid & (NCOPY - 1);
  unsigned int* wsw = (unsigned int*)wsf;
  if (t == 0) {
    float mm = wmin[0];
    for (int i = 1; i < TPB / 64; ++i) mm = fminf(mm, wmin[i]);
    atomicMin(&wsw[MINBASE + copy], __float_as_uint(mm));
  }
  if (t < G) {
    glbAddF(&wsf[copy * G + t], hsum[t]);
    glbAddU(&wsw[2 * NG + copy * G + t], hcnt[t]);
  } else if (t >= 64 && t < 64 + G) {
    int s = t - 64;
    glbAddF(&wsf[NG + copy * G + s], vsum[s]);
    glbAddU(&wsw[3 * NG + copy * G + s], vcnt[s]);
  }

  // ---- last-block finalize (replaces the crop_final launch) ----
  __syncthreads();   // compiler drains vmcnt before s_barrier -> this block's atomics are globally visible
  if (t == 0) {
    unsigned prev = __hip_atomic_fetch_add(&wsw[CTR], 1u, __ATOMIC_ACQ_REL, __HIP_MEMORY_SCOPE_AGENT);
    lastFlag = (prev == (unsigned)(NBLK - 1));
  }
  __syncthreads();
  if (!lastFlag) return;

  // global min over the 64 copy slots
  if (t < 64) {
    float v = __uint_as_float(atomLoadU(&wsu[MINBASE + t]));
    for (int off = 32; off; off >>= 1) v = fminf(v, __shfl_down(v, off));
    if (t == 0) sminv = v;
  }
  // 100 (fam,g) pairs x 4 chunks of 16 copies (agent atomic loads bypass L1)
  if (t < 400) {
    const int pair = t >> 2, chunk = t & 3;
    const int fam = pair >= G;
    const int g = fam ? pair - G : pair;
    const int sumBase = fam ? NG : 0;
    const int cntBase = (2 + fam) * NG;
    double s = 0.0; unsigned int c = 0;
#pragma unroll
    for (int i = 0; i < 16; ++i) {
      const int cp = chunk * 16 + i;
      s += (double)atomLoadF(&wsf[sumBase + cp * G + g]);
      c += atomLoadU(&wsu[cntBase + cp * G + g]);
    }
    psum[pair][chunk] = s;
    pcnt[pair][chunk] = c;
  }
  __syncthreads();

  if (t < 100) {
    double s = psum[t][0] + psum[t][1] + psum[t][2] + psum[t][3];
    double c = (double)(pcnt[t][0] + pcnt[t][1] + pcnt[t][2] + pcnt[t][3]);
    val[t] = s - (double)sminv * c;   // scale cancels in the cumsum ratio
  }
  __syncthreads();

  if (t == 0) {
    auto bounds = [&](const double* v, int& lowerI, int& upperI) {
      double tot = 0;
      for (int s = 0; s < G; ++s) tot += v[s];
      double c = 0; bool found = false; int last = -1; lowerI = 0;
      for (int s = 0; s < G; ++s) {
        c += v[s];
        double cc = c / tot;
        if (!found && cc >= 0.01) { lowerI = s; found = true; }
        if (cc <= 0.99) last = s;
      }
      upperI = (last < 0) ? (G + 1) : (last + 2);  // all-false reversed argmax -> 51
    };
    int lh, uh, lv, uv;
    bounds(&val[0], lh, uh);
    bounds(&val[G], lv, uv);

    const double* dRho = (const double*)(wsu + C0 + 300);
    const double* dSth = (const double*)(wsu + C0 + 400);
    const double* dCth = (const double*)(wsu + C0 + 500);
    const double* dStv = (const double*)(wsu + C0 + 600);
    const double* dCtv = (const double*)(wsu + C0 + 700);

    auto tn = [&](int i) { return ((G - i) % G + G) % G; };  // python a[-i]
    int ihmin = tn(lh), ihmax = tn(uh), ivmin = tn(lv), ivmax = tn(uv);

    // intersect(h-line, v-line): det = cos(t1)sin(t2) - cos(t2)sin(t1)
    auto inter = [&](int ih, int iv, float* o) {
      double r1 = dRho[ih], s1 = dSth[ih], c1 = dCth[ih];
      double r2 = dRho[iv], s2 = dStv[iv], c2 = dCtv[iv];
      double det = c1 * s2 - c2 * s1;
      o[0] = (float)((r1 * s2 - r2 * s1) / det);
      o[1] = (float)((r2 * c1 - r1 * c2) / det);
    };
    inter(ihmin, ivmin, out + 0);
    inter(ihmax, ivmin, out + 2);
    inter(ihmax, ivmax, out + 4);
    inter(ihmin, ivmax, out + 6);
  }
}

extern "C" void kernel_launch(void* const* d_in, const int* in_sizes, int n_in,
                              void* d_out, int out_size, void* d_ws, size_t ws_size,
                              hipStream_t stream) {
  const float* sp    = (const float*)d_in[0];
  const float* rmax  = (const float*)d_in[1];
  const float* rmin  = (const float*)d_in[2];
  const float* thmin = (const float*)d_in[3];
  const float* thmax = (const float*)d_in[4];
  const float* tvmin = (const float*)d_in[5];
  const float* tvmax = (const float*)d_in[6];
  float* wsf  = (float*)d_ws;
  float* outp = (float*)d_out;

  crop_init<<<(C0 + 255) / 256, 256, 0, stream>>>((unsigned int*)d_ws,
                                                  rmax, rmin, thmin, thmax, tvmin, tvmax);
  crop_main<<<NBLK, TPB, 0, stream>>>(sp, wsf, outp);
}

// Round 5
// 250.144 us; speedup vs baseline: 1.5969x; 1.5969x over previous
//
#include <hip/hip_runtime.h>
#include <math.h>

#define HH 6144
#define WW 6144
constexpr int G = 50;
constexpr int NCOPY = 64;
constexpr int NG = NCOPY * G;          // 3200
constexpr int BIG = 0x0FFFFFFF;
constexpr int MINBASE = 4 * NG;        // 12800: min slots (NCOPY uints)
constexpr int CTR = MINBASE + NCOPY;   // 12864: 64 slot counters
constexpr int MASTER = CTR + NCOPY;    // 12928: master counter
constexpr int C0 = MASTER + 2;         // 12930 (even -> 8B-aligned doubles)
// const tables (word offsets from C0):
//   dT   [0,100)    tan(th)      f64 x50
//   dRC  [100,200)  rho/cos(th)  f64 x50
//   fva  [200,250)  rho/sin(tv)  f32 x50
//   fvb  [250,300)  cos/sin(tv)  f32 x50
//   dRho [300,400)  rho          f64 x50
//   dSth [400,500)  sin(th)      f64 x50
//   dCth [500,600)  cos(th)      f64 x50
//   dStv [600,700)  sin(tv)      f64 x50
//   dCtv [700,800)  cos(tv)      f64 x50

constexpr int TPB  = 384;
constexpr int PXT  = 16;               // px per thread
constexpr int NF4  = WW / 4;           // 1536 float4 per row
constexpr int NBLK = HH;               // 1 row per block; NBLK/NCOPY = 96

// ALL global atomics relaxed — agent acquire/release on gfx950 emits L2-wide
// buffer_inv/buffer_wbl2 (per-XCD L2 non-coherent) and was the round-4 2.5x
// regression. Ordering instead: __syncthreads drains vmcnt(0), so each
// block's flush atomics are globally performed before its counter add issues.
__device__ inline void ldsAddF(float* p, float v)      { __hip_atomic_fetch_add(p, v, __ATOMIC_RELAXED, __HIP_MEMORY_SCOPE_WORKGROUP); }
__device__ inline void ldsAddU(unsigned* p, unsigned v){ __hip_atomic_fetch_add(p, v, __ATOMIC_RELAXED, __HIP_MEMORY_SCOPE_WORKGROUP); }
__device__ inline void glbAddF(float* p, float v)      { __hip_atomic_fetch_add(p, v, __ATOMIC_RELAXED, __HIP_MEMORY_SCOPE_AGENT); }
__device__ inline void glbAddU(unsigned* p, unsigned v){ __hip_atomic_fetch_add(p, v, __ATOMIC_RELAXED, __HIP_MEMORY_SCOPE_AGENT); }
__device__ inline unsigned glbAddCtr(unsigned* p)      { return __hip_atomic_fetch_add(p, 1u, __ATOMIC_RELAXED, __HIP_MEMORY_SCOPE_AGENT); }
__device__ inline float atomLoadF(const float* p)      { return __hip_atomic_load(p, __ATOMIC_RELAXED, __HIP_MEMORY_SCOPE_AGENT); }
__device__ inline unsigned atomLoadU(const unsigned* p){ return __hip_atomic_load(p, __ATOMIC_RELAXED, __HIP_MEMORY_SCOPE_AGENT); }

__global__ void crop_init(unsigned int* __restrict__ ws,
                          const float* __restrict__ p_rmax,
                          const float* __restrict__ p_rmin,
                          const float* __restrict__ p_thmin,
                          const float* __restrict__ p_thmax,
                          const float* __restrict__ p_tvmin,
                          const float* __restrict__ p_tvmax) {
  int i = blockIdx.x * 256 + threadIdx.x;
  if (i < MINBASE) ws[i] = 0u;
  else if (i < MINBASE + NCOPY) ws[i] = 0x7F800000u;   // +inf bits
  else if (i < C0) ws[i] = 0u;                         // counters + pad

  if (blockIdx.x == 0 && threadIdx.x < G) {
    int t = threadIdx.x;
    double u    = (double)t / (double)(G - 1);
    double rmax = (double)p_rmax[0], rmin = (double)p_rmin[0];
    double rho  = rmax + (rmin - rmax) * u;
    double th   = (double)p_thmin[0] + ((double)p_thmax[0] - (double)p_thmin[0]) * u;
    double tv   = (double)p_tvmin[0] + ((double)p_tvmax[0] - (double)p_tvmin[0]) * u;
    double cth = cos(th), sth = sin(th);
    double ctv = cos(tv), stv = sin(tv);
    double* dT   = (double*)(ws + C0);
    double* dRC  = (double*)(ws + C0 + 100);
    float*  fva  = (float*)(ws + C0 + 200);
    float*  fvb  = (float*)(ws + C0 + 250);
    double* dRho = (double*)(ws + C0 + 300);
    double* dSth = (double*)(ws + C0 + 400);
    double* dCth = (double*)(ws + C0 + 500);
    double* dStv = (double*)(ws + C0 + 600);
    double* dCtv = (double*)(ws + C0 + 700);
    dT[t]  = tan(th);
    dRC[t] = rho / cth;
    fva[t] = (float)(rho / stv);
    fvb[t] = (float)(ctv / stv);
    dRho[t] = rho; dSth[t] = sth; dCth[t] = cth; dStv[t] = stv; dCtv[t] = ctv;
  }
}

__launch_bounds__(TPB)
__global__ void crop_main(const float* __restrict__ sp,
                          float* __restrict__ wsf,
                          float* __restrict__ out) {
  __shared__ float4 srow[NF4];                 // row staging, XOR-swizzled slots
  __shared__ int pxh[G], pxv[G];               // boundaries, nonincreasing in g
  __shared__ float hsum[G + 1], vsum[G + 1];   // bin G = dropped (segment id 50)
  __shared__ unsigned int hcnt[G + 1], vcnt[G + 1];
  __shared__ float wmin[TPB / 64];
  __shared__ int lastFlag;
  __shared__ double valS[100];
  __shared__ unsigned int valC[100];
  __shared__ float sminv;

  const int t  = threadIdx.x;
  const int y  = blockIdx.x;
  const int yp = min(max(y, 1), HH - 2);       // edge-effect fix == clamp of coords
  const float fyp = (float)yp;

  // lane-contiguous coalesced loads: 4 float4 per thread, stride TPB slots
  const float4* rowp = (const float4*)(sp + (size_t)y * WW);
  float4 a0 = rowp[t], a1 = rowp[t + 384], a2 = rowp[t + 768], a3 = rowp[t + 1152];

  for (int i = t; i < G + 1; i += TPB) { hsum[i] = 0.f; vsum[i] = 0.f; hcnt[i] = 0u; vcnt[i] = 0u; }

  const unsigned int* wsu = (const unsigned int*)wsf;
  if (t < G) {                                 // overlaps global-load latency
    const double* dT  = (const double*)(wsu + C0);
    const double* dRC = (const double*)(wsu + C0 + 100);
    const float*  fva = (const float*)(wsu + C0 + 200);
    const float*  fvb = (const float*)(wsu + C0 + 250);

    // horizontal family: f64 fma + half-even rint (identical to passing rounds)
    double xg = rint(fma(-(double)yp, dT[t], dRC[t]));
    xg = fmin(fmax(xg, 0.0), (double)(WW - 1));
    int xi = (int)xg;
    pxh[t] = (xi <= 1) ? 0 : (xi >= WW - 1 ? BIG : xi);

    // vertical family: binary-search the EXACT f32 per-pixel condition
    float va = fva[t], vb = fvb[t];
    int lo = 1, hi = WW - 1;
    while (lo < hi) {
      int m = (lo + hi) >> 1;
      float yv = rintf(fmaf(-(float)m, vb, va));
      yv = fminf(fmaxf(yv, 0.f), (float)(HH - 1));
      if (yv <= fyp) hi = m; else lo = m + 1;
    }
    pxv[t] = (lo >= WW - 1) ? BIG : (lo == 1 ? 0 : lo);
  }

  // stage to LDS; slot swizzle s^((s>>3)&3) is an involution, conflict-free
  // (8 distinct bank-quads per 8 lanes) for both the write and read patterns.
  srow[(t)        ^ (((t)        >> 3) & 3)] = a0;
  srow[(t + 384)  ^ (((t + 384)  >> 3) & 3)] = a1;
  srow[(t + 768)  ^ (((t + 768)  >> 3) & 3)] = a2;
  srow[(t + 1152) ^ (((t + 1152) >> 3) & 3)] = a3;
  __syncthreads();

  // read back this thread's 16 contiguous pixels
  const int swr = (t >> 1) & 3;
  float4 q0 = srow[(4 * t + 0) ^ swr];
  float4 q1 = srow[(4 * t + 1) ^ swr];
  float4 q2 = srow[(4 * t + 2) ^ swr];
  float4 q3 = srow[(4 * t + 3) ^ swr];
  float px[PXT] = { q0.x,q0.y,q0.z,q0.w, q1.x,q1.y,q1.z,q1.w,
                    q2.x,q2.y,q2.z,q2.w, q3.x,q3.y,q3.z,q3.w };

  const int x0 = t * PXT;

  // bin at x0: lb = first g with px*[g] <= x0 (arrays nonincreasing in g)
  int lo = 0, hi = G;
  while (lo < hi) { int m = (lo + hi) >> 1; if (pxh[m] <= x0) hi = m; else lo = m + 1; }
  const int lbh = lo;
  const int nbh = (lbh > 0) ? pxh[lbh - 1] : BIG;
  const int kh  = min(nbh - x0, PXT);          // [1,PXT]; PXT => no crossing in run

  lo = 0; hi = G;
  while (lo < hi) { int m = (lo + hi) >> 1; if (pxv[m] <= x0) hi = m; else lo = m + 1; }
  const int lbv = lo;
  const int nbv = (lbv > 0) ? pxv[lbv - 1] : BIG;
  const int kv  = min(nbv - x0, PXT);

  const int sh = G - lbh, sv = G - lbv;

  float S = 0.f, Ah = 0.f, Av = 0.f, mn = 3.4e38f;
#pragma unroll
  for (int k = 0; k < PXT; ++k) {
    float v = px[k];
    mn = fminf(mn, v);
    S += v;
    if (k + 1 == kh) Ah = S;
    if (k + 1 == kv) Av = S;
  }

  ldsAddF(&hsum[sh], Ah); ldsAddU(&hcnt[sh], (unsigned)kh);
  if (kh < PXT) { ldsAddF(&hsum[sh + 1], S - Ah); ldsAddU(&hcnt[sh + 1], (unsigned)(PXT - kh)); }
  ldsAddF(&vsum[sv], Av); ldsAddU(&vcnt[sv], (unsigned)kv);
  if (kv < PXT) { ldsAddF(&vsum[sv + 1], S - Av); ldsAddU(&vcnt[sv + 1], (unsigned)(PXT - kv)); }

  // block min reduce (6 waves)
  float m = mn;
  for (int off = 32; off; off >>= 1) m = fminf(m, __shfl_down(m, off));
  if ((t & 63) == 0) wmin[t >> 6] = m;
  __syncthreads();

  const int copy = y & (NCOPY - 1);
  unsigned int* wsw = (unsigned int*)wsf;
  if (t == 0) {
    float mm = wmin[0];
    for (int i = 1; i < TPB / 64; ++i) mm = fminf(mm, wmin[i]);
    atomicMin(&wsw[MINBASE + copy], __float_as_uint(mm));
  }
  if (t < G) {
    glbAddF(&wsf[copy * G + t], hsum[t]);
    glbAddU(&wsw[2 * NG + copy * G + t], hcnt[t]);
  } else if (t >= 64 && t < 64 + G) {
    int s = t - 64;
    glbAddF(&wsf[NG + copy * G + s], vsum[s]);
    glbAddU(&wsw[3 * NG + copy * G + s], vcnt[s]);
  }

  // ---- fused finalize: two-level relaxed done-counter ----
  __syncthreads();   // vmcnt(0) drained -> this block's flush atomics are globally performed
  if (t == 0) {
    int last = 0;
    unsigned p1 = glbAddCtr(&wsw[CTR + copy]);        // 96 blocks per slot
    if (p1 == (unsigned)(NBLK / NCOPY - 1)) {
      unsigned p2 = glbAddCtr(&wsw[MASTER]);          // 64 slot-winners
      last = (p2 == (unsigned)(NCOPY - 1));
    }
    lastFlag = last;
  }
  __syncthreads();
  if (!lastFlag) return;

  // global min over the 64 copy slots
  if (t < 64) {
    float v = __uint_as_float(atomLoadU(&wsu[MINBASE + t]));
    for (int off = 32; off; off >>= 1) v = fminf(v, __shfl_down(v, off));
    if (t == 0) sminv = v;
  }
  // 100 (fam,g) pairs, each reduces its 64 copies (independent loads, unrolled)
  if (t < 100) {
    const int fam = t >= G;
    const int g = fam ? t - G : t;
    const int sumBase = fam ? NG : 0;
    const int cntBase = (2 + fam) * NG;
    double s = 0.0; unsigned int c = 0;
#pragma unroll 8
    for (int cp = 0; cp < NCOPY; ++cp) {
      s += (double)atomLoadF(&wsf[sumBase + cp * G + g]);
      c += atomLoadU(&wsu[cntBase + cp * G + g]);
    }
    valS[t] = s; valC[t] = c;
  }
  __syncthreads();

  if (t == 0) {
    const double mv = (double)sminv;
    auto bounds = [&](int base, int& lowerI, int& upperI) {
      double tot = 0;
      for (int s = 0; s < G; ++s) tot += valS[base + s] - mv * (double)valC[base + s];
      double c = 0; bool found = false; int last = -1; lowerI = 0;
      for (int s = 0; s < G; ++s) {
        c += valS[base + s] - mv * (double)valC[base + s];
        double cc = c / tot;
        if (!found && cc >= 0.01) { lowerI = s; found = true; }
        if (cc <= 0.99) last = s;
      }
      upperI = (last < 0) ? (G + 1) : (last + 2);  // all-false reversed argmax -> 51
    };
    int lh, uh, lv, uv;
    bounds(0, lh, uh);
    bounds(G, lv, uv);

    const double* dRho = (const double*)(wsu + C0 + 300);
    const double* dSth = (const double*)(wsu + C0 + 400);
    const double* dCth = (const double*)(wsu + C0 + 500);
    const double* dStv = (const double*)(wsu + C0 + 600);
    const double* dCtv = (const double*)(wsu + C0 + 700);

    auto tn = [&](int i) { return ((G - i) % G + G) % G; };  // python a[-i]
    int ihmin = tn(lh), ihmax = tn(uh), ivmin = tn(lv), ivmax = tn(uv);

    auto inter = [&](int ih, int iv, float* o) {
      double r1 = dRho[ih], s1 = dSth[ih], c1 = dCth[ih];
      double r2 = dRho[iv], s2 = dStv[iv], c2 = dCtv[iv];
      double det = c1 * s2 - c2 * s1;
      o[0] = (float)((r1 * s2 - r2 * s1) / det);
      o[1] = (float)((r2 * c1 - r1 * c2) / det);
    };
    inter(ihmin, ivmin, out + 0);
    inter(ihmax, ivmin, out + 2);
    inter(ihmax, ivmax, out + 4);
    inter(ihmin, ivmax, out + 6);
  }
}

extern "C" void kernel_launch(void* const* d_in, const int* in_sizes, int n_in,
                              void* d_out, int out_size, void* d_ws, size_t ws_size,
                              hipStream_t stream) {
  const float* sp    = (const float*)d_in[0];
  const float* rmax  = (const float*)d_in[1];
  const float* rmin  = (const float*)d_in[2];
  const float* thmin = (const float*)d_in[3];
  const float* thmax = (const float*)d_in[4];
  const float* tvmin = (const float*)d_in[5];
  const float* tvmax = (const float*)d_in[6];
  float* wsf  = (float*)d_ws;
  float* outp = (float*)d_out;

  crop_init<<<(C0 + 255) / 256, 256, 0, stream>>>((unsigned int*)d_ws,
                                                  rmax, rmin, thmin, thmax, tvmin, tvmax);
  crop_main<<<NBLK, TPB, 0, stream>>>(sp, wsf, outp);
}